// Round 1
// baseline (84.299 us; speedup 1.0000x reference)
//
#include <hip/hip_runtime.h>

#define NN   2048
#define EE   65536
#define EDIM 64
#define LL   5

// Kernel 1: dots[e][l] = sum_d edge_attr[e][d] * edge_vector[l][d]
// One wave (64 lanes) per edge row; lane-parallel over the 64-dim axis,
// butterfly shuffle reduce for all 5 l at once.
__global__ __launch_bounds__(256) void dots_kernel(
    const float* __restrict__ edge_attr,
    const float* __restrict__ edge_vector,
    float* __restrict__ dots) {
  const int lane = threadIdx.x & 63;
  const int wid  = (blockIdx.x * blockDim.x + threadIdx.x) >> 6;
  const int nw   = (gridDim.x * blockDim.x) >> 6;

  const float ev0 = edge_vector[0 * EDIM + lane];
  const float ev1 = edge_vector[1 * EDIM + lane];
  const float ev2 = edge_vector[2 * EDIM + lane];
  const float ev3 = edge_vector[3 * EDIM + lane];
  const float ev4 = edge_vector[4 * EDIM + lane];

  for (int e = wid; e < EE; e += nw) {
    const float a = edge_attr[e * EDIM + lane];
    float d0 = a * ev0, d1 = a * ev1, d2 = a * ev2, d3 = a * ev3, d4 = a * ev4;
#pragma unroll
    for (int s = 32; s >= 1; s >>= 1) {
      d0 += __shfl_xor(d0, s, 64);
      d1 += __shfl_xor(d1, s, 64);
      d2 += __shfl_xor(d2, s, 64);
      d3 += __shfl_xor(d3, s, 64);
      d4 += __shfl_xor(d4, s, 64);
    }
    if (lane < LL) {
      float dv = (lane == 0) ? d0 : (lane == 1) ? d1 : (lane == 2) ? d2
                : (lane == 3) ? d3 : d4;
      dots[e * LL + lane] = dv;
    }
  }
}

// Kernel 2: each thread handles 4 (i,j) pairs = 20 contiguous int32 indices
// (5x int4 vector loads), gathers from the L2-resident dots table with
// exec-masked loads (id==-1 lanes issue no request), writes float4.
__global__ __launch_bounds__(256) void pairs_kernel(
    const int* __restrict__ ept,
    const float* __restrict__ dots,
    float* __restrict__ out) {
  const long t = (long)blockIdx.x * blockDim.x + threadIdx.x;  // 0 .. N*N/4-1

  int buf[20];
  const int4* p = (const int4*)(ept + t * 20);
#pragma unroll
  for (int k = 0; k < 5; ++k) {
    int4 v = p[k];
    buf[4 * k + 0] = v.x;
    buf[4 * k + 1] = v.y;
    buf[4 * k + 2] = v.z;
    buf[4 * k + 3] = v.w;
  }

  float rr[4];
#pragma unroll
  for (int k = 0; k < 4; ++k) {
    float s = 0.f;
    int cnt = 0;
#pragma unroll
    for (int l = 0; l < LL; ++l) {
      const int id = buf[k * LL + l];
      if (id >= 0) {           // exec-masked: invalid lanes issue no gather
        s += dots[id * LL + l];
        ++cnt;
      }
    }
    rr[k] = (cnt > 0) ? s / ((float)cnt + 1e-10f) : 0.f;
  }
  *(float4*)(out + t * 4) = make_float4(rr[0], rr[1], rr[2], rr[3]);
}

extern "C" void kernel_launch(void* const* d_in, const int* in_sizes, int n_in,
                              void* d_out, int out_size, void* d_ws, size_t ws_size,
                              hipStream_t stream) {
  // d_in order: x(unused), edge_attr, edge_vector, edge_paths_tensor, edge_paths_length(unused)
  const float* edge_attr   = (const float*)d_in[1];
  const float* edge_vector = (const float*)d_in[2];
  const int*   ept         = (const int*)d_in[3];
  float* out  = (float*)d_out;
  float* dots = (float*)d_ws;  // E * L * 4 = 1.25 MB scratch

  // Kernel 1: 512 blocks x 256 threads = 2048 waves, 32 rows each.
  dots_kernel<<<512, 256, 0, stream>>>(edge_attr, edge_vector, dots);

  // Kernel 2: N*N/4 threads, 4 pairs per thread.
  const int total_threads = (NN * NN) / 4;  // 1,048,576
  pairs_kernel<<<total_threads / 256, 256, 0, stream>>>(ept, dots, out);
}

// Round 2
// 76.113 us; speedup vs baseline: 1.1076x; 1.1076x over previous
//
#include <hip/hip_runtime.h>

#define NN   2048
#define EE   65536
#define EDIM 64
#define LL   5

// Kernel 1: dots[e][l] = sum_d edge_attr[e][d] * edge_vector[l][d]
// One wave per edge (no loop) so 8 waves/SIMD hide the shuffle-chain latency.
__global__ __launch_bounds__(256) void dots_kernel(
    const float* __restrict__ edge_attr,
    const float* __restrict__ edge_vector,
    float* __restrict__ dots) {
  const int lane = threadIdx.x & 63;
  const int e    = (int)((blockIdx.x * blockDim.x + threadIdx.x) >> 6);

  const float ev0 = edge_vector[0 * EDIM + lane];
  const float ev1 = edge_vector[1 * EDIM + lane];
  const float ev2 = edge_vector[2 * EDIM + lane];
  const float ev3 = edge_vector[3 * EDIM + lane];
  const float ev4 = edge_vector[4 * EDIM + lane];

  const float a = edge_attr[e * EDIM + lane];
  float d0 = a * ev0, d1 = a * ev1, d2 = a * ev2, d3 = a * ev3, d4 = a * ev4;
#pragma unroll
  for (int s = 32; s >= 1; s >>= 1) {
    d0 += __shfl_xor(d0, s, 64);
    d1 += __shfl_xor(d1, s, 64);
    d2 += __shfl_xor(d2, s, 64);
    d3 += __shfl_xor(d3, s, 64);
    d4 += __shfl_xor(d4, s, 64);
  }
  if (lane < LL) {
    float dv = (lane == 0) ? d0 : (lane == 1) ? d1 : (lane == 2) ? d2
              : (lane == 3) ? d3 : d4;
    dots[e * LL + lane] = dv;
  }
}

// Kernel 2: 4 (i,j) pairs per thread. Branch-free: clamp index, load
// unconditionally (masked lanes broadcast-merge on dots[l]), cndmask the
// accumulate. All 20 gathers issue before any consumption -> full MLP.
__global__ __launch_bounds__(256) void pairs_kernel(
    const int* __restrict__ ept,
    const float* __restrict__ dots,
    float* __restrict__ out) {
  const long t = (long)blockIdx.x * blockDim.x + threadIdx.x;  // 0 .. N*N/4-1

  int buf[20];
  const int4* p = (const int4*)(ept + t * 20);
#pragma unroll
  for (int k = 0; k < 5; ++k) {
    int4 v = p[k];
    buf[4 * k + 0] = v.x;
    buf[4 * k + 1] = v.y;
    buf[4 * k + 2] = v.z;
    buf[4 * k + 3] = v.w;
  }

  float vals[20];
  int   msk[20];
#pragma unroll
  for (int q = 0; q < 20; ++q) {
    const int id   = buf[q];
    const int safe = (id < 0) ? 0 : id;
    const int l    = q - (q / LL) * LL;     // compile-time after unroll
    vals[q] = dots[safe * LL + l];          // unconditional, independent
    msk[q]  = (id >= 0);
  }

  float rr[4];
#pragma unroll
  for (int k = 0; k < 4; ++k) {
    float s = 0.f;
    int cnt = 0;
#pragma unroll
    for (int l = 0; l < LL; ++l) {
      s   += msk[k * LL + l] ? vals[k * LL + l] : 0.f;
      cnt += msk[k * LL + l];
    }
    rr[k] = (cnt > 0) ? s / ((float)cnt + 1e-10f) : 0.f;
  }
  *(float4*)(out + t * 4) = make_float4(rr[0], rr[1], rr[2], rr[3]);
}

extern "C" void kernel_launch(void* const* d_in, const int* in_sizes, int n_in,
                              void* d_out, int out_size, void* d_ws, size_t ws_size,
                              hipStream_t stream) {
  // d_in order: x(unused), edge_attr, edge_vector, edge_paths_tensor, edge_paths_length(unused)
  const float* edge_attr   = (const float*)d_in[1];
  const float* edge_vector = (const float*)d_in[2];
  const int*   ept         = (const int*)d_in[3];
  float* out  = (float*)d_out;
  float* dots = (float*)d_ws;  // E * L * 4 = 1.31 MB scratch

  // Kernel 1: one wave per edge -> 65536 waves = 16384 blocks.
  dots_kernel<<<EE / 4, 256, 0, stream>>>(edge_attr, edge_vector, dots);

  // Kernel 2: N*N/4 threads, 4 pairs per thread.
  const int total_threads = (NN * NN) / 4;  // 1,048,576
  pairs_kernel<<<total_threads / 256, 256, 0, stream>>>(ept, dots, out);
}

// Round 3
// 59.680 us; speedup vs baseline: 1.4125x; 1.2753x over previous
//
#include <hip/hip_runtime.h>

#define NN   2048
#define EE   65536
#define EDIM 64
#define LL   5

// Kernel 1: dots[e][l] = sum_d edge_attr[e][d] * edge_vector[l][d]
// 4 edges per wave: lane = (e_sub[2b], dgroup[4b]); float4 over d;
// 4 shuffle levels within 16-lane groups (6x fewer DS ops than full butterfly).
__global__ __launch_bounds__(256) void dots_kernel(
    const float* __restrict__ edge_attr,
    const float* __restrict__ edge_vector,
    float* __restrict__ dots) {
  const int lane = threadIdx.x & 63;
  const int wib  = threadIdx.x >> 6;   // wave in block: 0..3
  const int dg   = lane & 15;          // d-group: 4 floats each
  const int es   = lane >> 4;          // edge within wave: 0..3
  const int e    = blockIdx.x * 16 + wib * 4 + es;

  const float4 a = *(const float4*)(edge_attr + e * EDIM + dg * 4);
  float d[LL];
#pragma unroll
  for (int l = 0; l < LL; ++l) {
    const float4 ev = *(const float4*)(edge_vector + l * EDIM + dg * 4);
    d[l] = a.x * ev.x + a.y * ev.y + a.z * ev.z + a.w * ev.w;
  }
#pragma unroll
  for (int s = 1; s <= 8; s <<= 1) {
#pragma unroll
    for (int l = 0; l < LL; ++l) d[l] += __shfl_xor(d[l], s, 64);
  }
  if (dg == 0) {
#pragma unroll
    for (int l = 0; l < LL; ++l) dots[e * LL + l] = d[l];
  }
}

// Kernel 2: 4 (i,j) pairs per thread. All 20 gathers forced simultaneously
// live (20-operand asm barrier) -> one waitcnt after 20 issues -> MLP=20.
__global__ __launch_bounds__(256) void pairs_kernel(
    const int* __restrict__ ept,
    const float* __restrict__ dots,
    float* __restrict__ out) {
  const long t = (long)blockIdx.x * blockDim.x + threadIdx.x;  // 0 .. N*N/4-1

  const int4* p = (const int4*)(ept + t * 20);
  int buf[20];
#pragma unroll
  for (int k = 0; k < 5; ++k) {
    const int4 v = p[k];
    buf[4 * k + 0] = v.x;
    buf[4 * k + 1] = v.y;
    buf[4 * k + 2] = v.z;
    buf[4 * k + 3] = v.w;
  }

  float vals[20];
#pragma unroll
  for (int q = 0; q < 20; ++q) {
    const int id   = buf[q];
    const int safe = (id < 0) ? 0 : id;
    vals[q] = dots[safe * LL + (q % LL)];   // q%LL constant after unroll
  }
  // Force all 20 gather results live at once: loads cannot sink past this,
  // consumption cannot hoist above it -> single vmcnt wait for all 20.
  asm volatile("" : "+v"(vals[0]), "+v"(vals[1]), "+v"(vals[2]), "+v"(vals[3]),
                    "+v"(vals[4]), "+v"(vals[5]), "+v"(vals[6]), "+v"(vals[7]),
                    "+v"(vals[8]), "+v"(vals[9]), "+v"(vals[10]), "+v"(vals[11]),
                    "+v"(vals[12]), "+v"(vals[13]), "+v"(vals[14]), "+v"(vals[15]),
                    "+v"(vals[16]), "+v"(vals[17]), "+v"(vals[18]), "+v"(vals[19]));

  float rr[4];
#pragma unroll
  for (int k = 0; k < 4; ++k) {
    float s = 0.f;
    int cnt = 0;
#pragma unroll
    for (int l = 0; l < LL; ++l) {
      const int m = (buf[k * LL + l] >= 0);
      s   += m ? vals[k * LL + l] : 0.f;
      cnt += m;
    }
    rr[k] = (cnt > 0) ? s / ((float)cnt + 1e-10f) : 0.f;
  }
  *(float4*)(out + t * 4) = make_float4(rr[0], rr[1], rr[2], rr[3]);
}

extern "C" void kernel_launch(void* const* d_in, const int* in_sizes, int n_in,
                              void* d_out, int out_size, void* d_ws, size_t ws_size,
                              hipStream_t stream) {
  // d_in order: x(unused), edge_attr, edge_vector, edge_paths_tensor, edge_paths_length(unused)
  const float* edge_attr   = (const float*)d_in[1];
  const float* edge_vector = (const float*)d_in[2];
  const int*   ept         = (const int*)d_in[3];
  float* out  = (float*)d_out;
  float* dots = (float*)d_ws;  // E * L * 4 = 1.31 MB scratch

  // Kernel 1: 16 edges per block (4 per wave) -> 4096 blocks.
  dots_kernel<<<EE / 16, 256, 0, stream>>>(edge_attr, edge_vector, dots);

  // Kernel 2: N*N/4 threads, 4 pairs per thread.
  const int total_threads = (NN * NN) / 4;  // 1,048,576
  pairs_kernel<<<total_threads / 256, 256, 0, stream>>>(ept, dots, out);
}